// Round 5
// baseline (139.216 us; speedup 1.0000x reference)
//
#include <hip/hip_runtime.h>
#include <hip/hip_bf16.h>

#define L_DIM 2048
#define D_DIM 2048
#define B_DIM 2
#define H_DIM 8
#define NT 16            // 2048/128 tiles per dim
#define NPAIR 136        // NT*(NT+1)/2 triangular tiles
#define NRED 128         // reducer blocks per batch (4 waves/CU machine-wide)
#define EPSV 1e-6f

using bf16x8 = __attribute__((ext_vector_type(8))) __bf16;
using f32x4  = __attribute__((ext_vector_type(4))) float;

__device__ inline void gload_lds16(const void* g, void* l) {
    __builtin_amdgcn_global_load_lds(
        (const __attribute__((address_space(1))) void*)g,
        (__attribute__((address_space(3))) void*)l, 16, 0, 0);
}

// round-to-nearest-even f32 -> bf16 (finite inputs)
__device__ inline ushort f2bf(float f) {
    unsigned int u = __float_as_uint(f);
    unsigned int lsb = (u >> 16) & 1u;
    u += 0x7fffu + lsb;
    return (ushort)(u >> 16);
}
__device__ inline float bf2f(ushort u) {
    return __uint_as_float(((unsigned int)u) << 16);
}

// ---------------- K1: row-normalize x -> bf16; zero the f64 accumulators -------------
__global__ __launch_bounds__(256) void k_normalize(const float* __restrict__ x,
                                                   ushort* __restrict__ xu,
                                                   double* __restrict__ sums) {
    const int row = blockIdx.x;            // b*L + l
    const int t   = threadIdx.x;
    const float* xr = x + (size_t)row * D_DIM;
    float4 v0 = ((const float4*)xr)[t];
    float4 v1 = ((const float4*)xr)[t + 256];
    float ss = v0.x*v0.x + v0.y*v0.y + v0.z*v0.z + v0.w*v0.w
             + v1.x*v1.x + v1.y*v1.y + v1.z*v1.z + v1.w*v1.w;
    #pragma unroll
    for (int off = 32; off; off >>= 1) ss += __shfl_down(ss, off);
    __shared__ float red[4];
    __shared__ float s_inv;
    if ((t & 63) == 0) red[t >> 6] = ss;
    __syncthreads();
    if (t == 0) {
        float nrm = sqrtf(red[0] + red[1] + red[2] + red[3]);
        nrm = fmaxf(nrm, EPSV);
        s_inv = 1.0f / nrm;
        if (row == 0) { sums[0] = 0.0; sums[1] = 0.0; sums[2] = 0.0; sums[3] = 0.0; }
    }
    __syncthreads();
    const float inv = s_inv;
    ushort* xo = xu + (size_t)row * D_DIM;
    ushort4 o0, o1;
    o0.x = f2bf(v0.x * inv); o0.y = f2bf(v0.y * inv);
    o0.z = f2bf(v0.z * inv); o0.w = f2bf(v0.w * inv);
    o1.x = f2bf(v1.x * inv); o1.y = f2bf(v1.y * inv);
    o1.z = f2bf(v1.z * inv); o1.w = f2bf(v1.w * inv);
    ((ushort4*)xo)[t]       = o0;
    ((ushort4*)xo)[t + 256] = o1;
}

// ---- K2 mixed grid: [0,NRED) attn-mean reducers | [NRED,NRED+NPAIR) sym GEMM tiles --
__global__ __launch_bounds__(256) void k_mixed(const ushort* __restrict__ Xu,
                                               const float* __restrict__ attn,
                                               float* __restrict__ Kout,
                                               double* __restrict__ sums,
                                               ushort* __restrict__ Amean) {
    __shared__ __align__(16) ushort lds_a[128 * 32];
    __shared__ __align__(16) ushort lds_b[128 * 32];
    const int t = threadIdx.x;
    const int batch = blockIdx.z;

    if (blockIdx.x < NRED) {
        // ---------------- reducer: Amean[b,l,c] = mean_h attn[b,h,l,c] (bf16) --------
        const float* ab = attn + (size_t)batch * H_DIM * L_DIM * L_DIM;
        ushort* am = Amean + (size_t)batch * L_DIM * L_DIM;
        int i = blockIdx.x * 256 + t;        // exact: 32 iterations cover L*L/4
        #pragma unroll 2
        for (int j = 0; j < 32; ++j, i += NRED * 256) {
            float4 s = {0.f, 0.f, 0.f, 0.f};
            #pragma unroll
            for (int h = 0; h < H_DIM; ++h) {
                const float4 v = ((const float4*)(ab + (size_t)h * L_DIM * L_DIM))[i];
                s.x += v.x; s.y += v.y; s.z += v.z; s.w += v.w;
            }
            ushort4 o;
            o.x = f2bf(s.x * 0.125f); o.y = f2bf(s.y * 0.125f);
            o.z = f2bf(s.z * 0.125f); o.w = f2bf(s.w * 0.125f);
            ((ushort4*)am)[i] = o;
        }
        return;
    }

    // ---------------- GEMM tile (upper-triangular + mirror) --------------------------
    const int lane = t & 63;
    const int w    = t >> 6;
    const int wr   = w >> 1, wc = w & 1;       // 2x2 waves, 64x64 each
    int ti = 0, rem = blockIdx.x - NRED;
    while (rem >= NT - ti) { rem -= NT - ti; ++ti; }
    const int tj = ti + rem;
    const int bRow = ti * 128;
    const int bCol = tj * 128;
    const bool diag = (ti == tj);
    const ushort* Xb = Xu + (size_t)batch * L_DIM * D_DIM;

    const int srow = t >> 2;                   // 0..63 panel row
    // pre-swizzled global chunk: LDS slot (t&3) of row srow holds chunk (t&3)^((srow>>1)&3)
    const int scol = ((t & 3) ^ ((srow >> 1) & 3)) * 8;
    const ushort* gA0 = Xb + (size_t)(bRow + srow)      * D_DIM + scol;
    const ushort* gA1 = Xb + (size_t)(bRow + 64 + srow) * D_DIM + scol;
    const ushort* gB0 = Xb + (size_t)(bCol + srow)      * D_DIM + scol;
    const ushort* gB1 = Xb + (size_t)(bCol + 64 + srow) * D_DIM + scol;
    ushort* lA0 = lds_a + t * 8;
    ushort* lA1 = lds_a + 64 * 32 + t * 8;
    ushort* lB0 = lds_b + t * 8;
    ushort* lB1 = lds_b + 64 * 32 + t * 8;

    f32x4 acc[4][4] = {};
    const int frow = lane & 15;
    const int fk   = lane >> 4;
    const int fx   = (frow >> 1) & 3;          // read-side XOR key: 2-way max per phase

    for (int kt = 0; kt < D_DIM / 32; ++kt) {
        __syncthreads();                       // protect LDS before overwrite
        const size_t ko = (size_t)kt * 32;
        gload_lds16(gA0 + ko, lA0);
        gload_lds16(gA1 + ko, lA1);
        gload_lds16(gB0 + ko, lB0);
        gload_lds16(gB1 + ko, lB1);
        __syncthreads();                       // vmcnt(0) drain at barrier
        bf16x8 a[4], b[4];
        #pragma unroll
        for (int m = 0; m < 4; ++m)
            a[m] = *(const bf16x8*)&lds_a[(wr * 64 + m * 16 + frow) * 32 + (fk ^ fx) * 8];
        #pragma unroll
        for (int n = 0; n < 4; ++n)
            b[n] = *(const bf16x8*)&lds_b[(wc * 64 + n * 16 + frow) * 32 + (fk ^ fx) * 8];
        #pragma unroll
        for (int m = 0; m < 4; ++m)
            #pragma unroll
            for (int n = 0; n < 4; ++n)
                acc[m][n] = __builtin_amdgcn_mfma_f32_16x16x32_bf16(a[m], b[n], acc[m][n], 0, 0, 0);
    }

    float* Kb = Kout + (size_t)batch * L_DIM * L_DIM;
    float ps = 0.f, pss = 0.f;
    #pragma unroll
    for (int m = 0; m < 4; ++m) {
        #pragma unroll
        for (int n = 0; n < 4; ++n) {
            #pragma unroll
            for (int j = 0; j < 4; ++j) {
                const int r = bRow + wr * 64 + m * 16 + fk * 4 + j;
                const int c = bCol + wc * 64 + n * 16 + frow;
                const float v = acc[m][n][j];
                Kb[(size_t)r * L_DIM + c] = v;
                ps += v; pss += v * v;
            }
            if (!diag) {
                // mirror: K[c][r..r+3] = acc[m][n][0..3] — contiguous float4
                const int rr  = bCol + wc * 64 + n * 16 + frow;
                const int cc0 = bRow + wr * 64 + m * 16 + fk * 4;
                *(float4*)&Kb[(size_t)rr * L_DIM + cc0] = *(float4*)&acc[m][n];
            }
        }
    }
    if (!diag) { ps *= 2.f; pss *= 2.f; }      // off-diag values appear twice in K
    #pragma unroll
    for (int off = 32; off; off >>= 1) {
        ps  += __shfl_down(ps, off);
        pss += __shfl_down(pss, off);
    }
    __shared__ float redS[4], redSS[4];
    if (lane == 0) { redS[w] = ps; redSS[w] = pss; }
    __syncthreads();
    if (t == 0) {
        atomicAdd(&sums[batch * 2],     (double)(redS[0] + redS[1] + redS[2] + redS[3]));
        atomicAdd(&sums[batch * 2 + 1], (double)(redSS[0] + redSS[1] + redSS[2] + redSS[3]));
    }
}

// ---------------- K3: K_norm in place; dot(Amean,K) -> cos_align, gate ---------------
__global__ __launch_bounds__(256) void k_epilogue(float* __restrict__ out,
                                                  const ushort* __restrict__ Amean,
                                                  const double* __restrict__ sums,
                                                  const float* __restrict__ Wp,
                                                  const float* __restrict__ bp) {
    const int row = blockIdx.x;              // b*L + l
    const int b = row >> 11;
    const int t = threadIdx.x;

    const double N = (double)L_DIM * (double)L_DIM;
    const double mean_d = sums[b * 2] / N;
    double var = (sums[b * 2 + 1] - N * mean_d * mean_d) / (N - 1.0);
    var = var > 0.0 ? var : 0.0;
    float sd = (float)sqrt(var);
    sd = fmaxf(sd, EPSV);
    const float inv_std = 1.0f / sd;
    const float mean = (float)mean_d;

    float* Krow = out + 2 * B_DIM * L_DIM + (size_t)row * L_DIM;
    const ushort* arow = Amean + (size_t)row * L_DIM;

    // 8 elements per thread: dot with raw K, then normalize in place
    float4 k0 = ((const float4*)Krow)[t * 2];
    float4 k1 = ((const float4*)Krow)[t * 2 + 1];
    const ushort4 a0 = ((const ushort4*)arow)[t * 2];
    const ushort4 a1 = ((const ushort4*)arow)[t * 2 + 1];
    float dot = bf2f(a0.x) * k0.x + bf2f(a0.y) * k0.y + bf2f(a0.z) * k0.z + bf2f(a0.w) * k0.w
              + bf2f(a1.x) * k1.x + bf2f(a1.y) * k1.y + bf2f(a1.z) * k1.z + bf2f(a1.w) * k1.w;
    float4 n0, n1;
    n0.x = (k0.x - mean) * inv_std; n0.y = (k0.y - mean) * inv_std;
    n0.z = (k0.z - mean) * inv_std; n0.w = (k0.w - mean) * inv_std;
    n1.x = (k1.x - mean) * inv_std; n1.y = (k1.y - mean) * inv_std;
    n1.z = (k1.z - mean) * inv_std; n1.w = (k1.w - mean) * inv_std;
    ((float4*)Krow)[t * 2]     = n0;
    ((float4*)Krow)[t * 2 + 1] = n1;

    #pragma unroll
    for (int off = 32; off; off >>= 1) dot += __shfl_down(dot, off);
    __shared__ float red[4];
    if ((t & 63) == 0) red[t >> 6] = dot;
    __syncthreads();
    if (t == 0) {
        const float dotv = red[0] + red[1] + red[2] + red[3];
        const float ca = (dotv - mean) * inv_std;      // uses sum_c A == 1
        out[B_DIM * L_DIM + row] = ca;                 // cos_align
        const float z = Wp[0] * ca + bp[0];
        out[row] = 1.0f / (1.0f + expf(-z));           // gate
    }
}

extern "C" void kernel_launch(void* const* d_in, const int* in_sizes, int n_in,
                              void* d_out, int out_size, void* d_ws, size_t ws_size,
                              hipStream_t stream) {
    const float* x    = (const float*)d_in[0];
    const float* attn = (const float*)d_in[1];
    const float* W    = (const float*)d_in[2];
    const float* bb   = (const float*)d_in[3];
    float* out = (float*)d_out;

    const size_t XU_BYTES = (size_t)B_DIM * L_DIM * D_DIM * 2;            // 16.78 MB
    ushort* xu    = (ushort*)d_ws;
    double* sums  = (double*)((char*)d_ws + XU_BYTES);
    ushort* Amean = (ushort*)((char*)d_ws + XU_BYTES + 256);              // 16.78 MB bf16
    float*  Kbuf  = out + 2 * B_DIM * L_DIM;                              // K in K_norm slot

    hipLaunchKernelGGL(k_normalize, dim3(B_DIM * L_DIM), dim3(256), 0, stream,
                       x, xu, sums);
    hipLaunchKernelGGL(k_mixed, dim3(NRED + NPAIR, 1, B_DIM), dim3(256), 0, stream,
                       xu, attn, Kbuf, sums, Amean);
    hipLaunchKernelGGL(k_epilogue, dim3(B_DIM * L_DIM), dim3(256), 0, stream,
                       out, Amean, sums, W, bb);
}

// Round 6
// 122.131 us; speedup vs baseline: 1.1399x; 1.1399x over previous
//
#include <hip/hip_runtime.h>
#include <hip/hip_bf16.h>

#define L_DIM 2048
#define D_DIM 2048
#define B_DIM 2
#define H_DIM 8
#define NT 16            // 2048/128 tiles per dim
#define NPAIR 136        // NT*(NT+1)/2 triangular tiles
#define NRED 512         // reducer blocks per batch (fine-grained, proven in R4)
#define NKT (D_DIM / 32) // 64 K-steps
#define EPSV 1e-6f

using bf16x8 = __attribute__((ext_vector_type(8))) __bf16;
using f32x4  = __attribute__((ext_vector_type(4))) float;

__device__ inline void gload_lds16(const void* g, void* l) {
    __builtin_amdgcn_global_load_lds(
        (const __attribute__((address_space(1))) void*)g,
        (__attribute__((address_space(3))) void*)l, 16, 0, 0);
}

// round-to-nearest-even f32 -> bf16 (finite inputs)
__device__ inline ushort f2bf(float f) {
    unsigned int u = __float_as_uint(f);
    unsigned int lsb = (u >> 16) & 1u;
    u += 0x7fffu + lsb;
    return (ushort)(u >> 16);
}
__device__ inline float bf2f(ushort u) {
    return __uint_as_float(((unsigned int)u) << 16);
}

// ---------------- K1: row-normalize x -> bf16; zero the f64 accumulators -------------
__global__ __launch_bounds__(256) void k_normalize(const float* __restrict__ x,
                                                   ushort* __restrict__ xu,
                                                   double* __restrict__ sums) {
    const int row = blockIdx.x;            // b*L + l
    const int t   = threadIdx.x;
    const float* xr = x + (size_t)row * D_DIM;
    float4 v0 = ((const float4*)xr)[t];
    float4 v1 = ((const float4*)xr)[t + 256];
    float ss = v0.x*v0.x + v0.y*v0.y + v0.z*v0.z + v0.w*v0.w
             + v1.x*v1.x + v1.y*v1.y + v1.z*v1.z + v1.w*v1.w;
    #pragma unroll
    for (int off = 32; off; off >>= 1) ss += __shfl_down(ss, off);
    __shared__ float red[4];
    __shared__ float s_inv;
    if ((t & 63) == 0) red[t >> 6] = ss;
    __syncthreads();
    if (t == 0) {
        float nrm = sqrtf(red[0] + red[1] + red[2] + red[3]);
        nrm = fmaxf(nrm, EPSV);
        s_inv = 1.0f / nrm;
        if (row == 0) { sums[0] = 0.0; sums[1] = 0.0; sums[2] = 0.0; sums[3] = 0.0; }
    }
    __syncthreads();
    const float inv = s_inv;
    ushort* xo = xu + (size_t)row * D_DIM;
    ushort4 o0, o1;
    o0.x = f2bf(v0.x * inv); o0.y = f2bf(v0.y * inv);
    o0.z = f2bf(v0.z * inv); o0.w = f2bf(v0.w * inv);
    o1.x = f2bf(v1.x * inv); o1.y = f2bf(v1.y * inv);
    o1.z = f2bf(v1.z * inv); o1.w = f2bf(v1.w * inv);
    ((ushort4*)xo)[t]       = o0;
    ((ushort4*)xo)[t + 256] = o1;
}

// ---- K2 mixed grid: [0,NPAIR) sym GEMM tiles | [NPAIR,NPAIR+NRED) attn-mean reducers
__global__ __launch_bounds__(256) void k_mixed(const ushort* __restrict__ Xu,
                                               const float* __restrict__ attn,
                                               float* __restrict__ Kout,
                                               double* __restrict__ sums,
                                               ushort* __restrict__ Amean) {
    __shared__ __align__(16) ushort lds_a[2][128 * 32];
    __shared__ __align__(16) ushort lds_b[2][128 * 32];
    const int t = threadIdx.x;
    const int batch = blockIdx.z;

    if (blockIdx.x >= NPAIR) {
        // ---------------- reducer: Amean[b,l,c] = mean_h attn[b,h,l,c] (bf16) --------
        const int rid = blockIdx.x - NPAIR;
        const float* ab = attn + (size_t)batch * H_DIM * L_DIM * L_DIM;
        ushort* am = Amean + (size_t)batch * L_DIM * L_DIM;
        const int n4 = L_DIM * L_DIM / 4;
        for (int i = rid * 256 + t; i < n4; i += NRED * 256) {   // 8 exact iters
            float4 s = {0.f, 0.f, 0.f, 0.f};
            #pragma unroll
            for (int h = 0; h < H_DIM; ++h) {
                const float4 v = ((const float4*)(ab + (size_t)h * L_DIM * L_DIM))[i];
                s.x += v.x; s.y += v.y; s.z += v.z; s.w += v.w;
            }
            ushort4 o;
            o.x = f2bf(s.x * 0.125f); o.y = f2bf(s.y * 0.125f);
            o.z = f2bf(s.z * 0.125f); o.w = f2bf(s.w * 0.125f);
            ((ushort4*)am)[i] = o;
        }
        return;
    }

    // ---------------- GEMM tile (upper-triangular + mirror), 2-phase pipelined -------
    const int lane = t & 63;
    const int w    = t >> 6;
    const int wr   = w >> 1, wc = w & 1;       // 2x2 waves, 64x64 each
    int ti = 0, rem = blockIdx.x;
    while (rem >= NT - ti) { rem -= NT - ti; ++ti; }
    const int tj = ti + rem;
    const int bRow = ti * 128;
    const int bCol = tj * 128;
    const bool diag = (ti == tj);
    const ushort* Xb = Xu + (size_t)batch * L_DIM * D_DIM;

    const int srow = t >> 2;                   // 0..63 panel row
    // store-side swizzle: LDS slot (t&3) of row srow receives chunk (t&3)^((srow>>1)&3)
    const int scol = ((t & 3) ^ ((srow >> 1) & 3)) * 8;
    const ushort* gA0 = Xb + (size_t)(bRow + srow)      * D_DIM + scol;
    const ushort* gA1 = Xb + (size_t)(bRow + 64 + srow) * D_DIM + scol;
    const ushort* gB0 = Xb + (size_t)(bCol + srow)      * D_DIM + scol;
    const ushort* gB1 = Xb + (size_t)(bCol + 64 + srow) * D_DIM + scol;
    const int ldst = t * 8;

    f32x4 acc[4][4] = {};
    const int frow = lane & 15;
    const int fk   = lane >> 4;
    const int fx   = (frow >> 1) & 3;          // read-side XOR key (conflict-free)

    auto STAGE = [&](int buf, int kt) {
        const size_t ko = (size_t)kt * 32;
        gload_lds16(gA0 + ko, &lds_a[buf][ldst]);
        gload_lds16(gA1 + ko, &lds_a[buf][64 * 32 + ldst]);
        gload_lds16(gB0 + ko, &lds_b[buf][ldst]);
        gload_lds16(gB1 + ko, &lds_b[buf][64 * 32 + ldst]);
    };
    auto COMPUTE = [&](int buf) {
        bf16x8 a[4], b[4];
        #pragma unroll
        for (int m = 0; m < 4; ++m)
            a[m] = *(const bf16x8*)&lds_a[buf][(wr * 64 + m * 16 + frow) * 32 + (fk ^ fx) * 8];
        #pragma unroll
        for (int n = 0; n < 4; ++n)
            b[n] = *(const bf16x8*)&lds_b[buf][(wc * 64 + n * 16 + frow) * 32 + (fk ^ fx) * 8];
        #pragma unroll
        for (int m = 0; m < 4; ++m)
            #pragma unroll
            for (int n = 0; n < 4; ++n)
                acc[m][n] = __builtin_amdgcn_mfma_f32_16x16x32_bf16(a[m], b[n], acc[m][n], 0, 0, 0);
    };

    STAGE(0, 0);
    __syncthreads();                           // vmcnt(0) drain: buf0 ready
    for (int kt = 0; kt < NKT; kt += 2) {
        STAGE(1, kt + 1);                      // kt+1 < NKT always (NKT even)
        COMPUTE(0);
        __syncthreads();                       // drains prefetch; syncs LDS reuse
        if (kt + 2 < NKT) STAGE(0, kt + 2);
        COMPUTE(1);
        __syncthreads();
    }

    float* Kb = Kout + (size_t)batch * L_DIM * L_DIM;
    float ps = 0.f, pss = 0.f;
    #pragma unroll
    for (int m = 0; m < 4; ++m) {
        #pragma unroll
        for (int n = 0; n < 4; ++n) {
            #pragma unroll
            for (int j = 0; j < 4; ++j) {
                const int r = bRow + wr * 64 + m * 16 + fk * 4 + j;
                const int c = bCol + wc * 64 + n * 16 + frow;
                const float v = acc[m][n][j];
                Kb[(size_t)r * L_DIM + c] = v;
                ps += v; pss += v * v;
            }
            if (!diag) {
                // mirror: K[c][r..r+3] = acc[m][n][0..3] — contiguous float4
                const int rr  = bCol + wc * 64 + n * 16 + frow;
                const int cc0 = bRow + wr * 64 + m * 16 + fk * 4;
                *(float4*)&Kb[(size_t)rr * L_DIM + cc0] = *(float4*)&acc[m][n];
            }
        }
    }
    if (!diag) { ps *= 2.f; pss *= 2.f; }      // off-diag values appear twice in K
    #pragma unroll
    for (int off = 32; off; off >>= 1) {
        ps  += __shfl_down(ps, off);
        pss += __shfl_down(pss, off);
    }
    __shared__ float redS[4], redSS[4];
    if (lane == 0) { redS[w] = ps; redSS[w] = pss; }
    __syncthreads();
    if (t == 0) {
        atomicAdd(&sums[batch * 2],     (double)(redS[0] + redS[1] + redS[2] + redS[3]));
        atomicAdd(&sums[batch * 2 + 1], (double)(redSS[0] + redSS[1] + redSS[2] + redSS[3]));
    }
}

// ---------------- K3: K_norm in place; dot(Amean,K) -> cos_align, gate ---------------
__global__ __launch_bounds__(256) void k_epilogue(float* __restrict__ out,
                                                  const ushort* __restrict__ Amean,
                                                  const double* __restrict__ sums,
                                                  const float* __restrict__ Wp,
                                                  const float* __restrict__ bp) {
    const int row = blockIdx.x;              // b*L + l
    const int b = row >> 11;
    const int t = threadIdx.x;

    const double N = (double)L_DIM * (double)L_DIM;
    const double mean_d = sums[b * 2] / N;
    double var = (sums[b * 2 + 1] - N * mean_d * mean_d) / (N - 1.0);
    var = var > 0.0 ? var : 0.0;
    float sd = (float)sqrt(var);
    sd = fmaxf(sd, EPSV);
    const float inv_std = 1.0f / sd;
    const float mean = (float)mean_d;

    float* Krow = out + 2 * B_DIM * L_DIM + (size_t)row * L_DIM;
    const ushort* arow = Amean + (size_t)row * L_DIM;

    // 8 elements per thread: dot with raw K, then normalize in place
    float4 k0 = ((const float4*)Krow)[t * 2];
    float4 k1 = ((const float4*)Krow)[t * 2 + 1];
    const ushort4 a0 = ((const ushort4*)arow)[t * 2];
    const ushort4 a1 = ((const ushort4*)arow)[t * 2 + 1];
    float dot = bf2f(a0.x) * k0.x + bf2f(a0.y) * k0.y + bf2f(a0.z) * k0.z + bf2f(a0.w) * k0.w
              + bf2f(a1.x) * k1.x + bf2f(a1.y) * k1.y + bf2f(a1.z) * k1.z + bf2f(a1.w) * k1.w;
    float4 n0, n1;
    n0.x = (k0.x - mean) * inv_std; n0.y = (k0.y - mean) * inv_std;
    n0.z = (k0.z - mean) * inv_std; n0.w = (k0.w - mean) * inv_std;
    n1.x = (k1.x - mean) * inv_std; n1.y = (k1.y - mean) * inv_std;
    n1.z = (k1.z - mean) * inv_std; n1.w = (k1.w - mean) * inv_std;
    ((float4*)Krow)[t * 2]     = n0;
    ((float4*)Krow)[t * 2 + 1] = n1;

    #pragma unroll
    for (int off = 32; off; off >>= 1) dot += __shfl_down(dot, off);
    __shared__ float red[4];
    if ((t & 63) == 0) red[t >> 6] = dot;
    __syncthreads();
    if (t == 0) {
        const float dotv = red[0] + red[1] + red[2] + red[3];
        const float ca = (dotv - mean) * inv_std;      // uses sum_c A == 1
        out[B_DIM * L_DIM + row] = ca;                 // cos_align
        const float z = Wp[0] * ca + bp[0];
        out[row] = 1.0f / (1.0f + expf(-z));           // gate
    }
}

extern "C" void kernel_launch(void* const* d_in, const int* in_sizes, int n_in,
                              void* d_out, int out_size, void* d_ws, size_t ws_size,
                              hipStream_t stream) {
    const float* x    = (const float*)d_in[0];
    const float* attn = (const float*)d_in[1];
    const float* W    = (const float*)d_in[2];
    const float* bb   = (const float*)d_in[3];
    float* out = (float*)d_out;

    const size_t XU_BYTES = (size_t)B_DIM * L_DIM * D_DIM * 2;            // 16.78 MB
    ushort* xu    = (ushort*)d_ws;
    double* sums  = (double*)((char*)d_ws + XU_BYTES);
    ushort* Amean = (ushort*)((char*)d_ws + XU_BYTES + 256);              // 16.78 MB bf16
    float*  Kbuf  = out + 2 * B_DIM * L_DIM;                              // K in K_norm slot

    hipLaunchKernelGGL(k_normalize, dim3(B_DIM * L_DIM), dim3(256), 0, stream,
                       x, xu, sums);
    hipLaunchKernelGGL(k_mixed, dim3(NPAIR + NRED, 1, B_DIM), dim3(256), 0, stream,
                       xu, attn, Kbuf, sums, Amean);
    hipLaunchKernelGGL(k_epilogue, dim3(B_DIM * L_DIM), dim3(256), 0, stream,
                       out, Amean, sums, W, bb);
}

// Round 7
// 109.468 us; speedup vs baseline: 1.2718x; 1.1157x over previous
//
#include <hip/hip_runtime.h>
#include <hip/hip_bf16.h>

#define L_DIM 2048
#define D_DIM 2048
#define B_DIM 2
#define H_DIM 8
#define NT 16            // 2048/128 tiles per dim
#define NPAIR 136        // NT*(NT+1)/2 triangular tiles
#define NRED 512         // reducer blocks per batch
#define NKT (D_DIM / 32) // 64 K-steps
#define EPSV 1e-6f

using bf16x8 = __attribute__((ext_vector_type(8))) __bf16;
using f32x4  = __attribute__((ext_vector_type(4))) float;
using f4     = __attribute__((ext_vector_type(4))) float;
using us4    = __attribute__((ext_vector_type(4))) unsigned short;

__device__ inline void gload_lds16(const void* g, void* l) {
    __builtin_amdgcn_global_load_lds(
        (const __attribute__((address_space(1))) void*)g,
        (__attribute__((address_space(3))) void*)l, 16, 0, 0);
}

// round-to-nearest-even f32 -> bf16 (finite inputs)
__device__ inline ushort f2bf(float f) {
    unsigned int u = __float_as_uint(f);
    unsigned int lsb = (u >> 16) & 1u;
    u += 0x7fffu + lsb;
    return (ushort)(u >> 16);
}
__device__ inline float bf2f(ushort u) {
    return __uint_as_float(((unsigned int)u) << 16);
}

// ---------------- K1: row-normalize x -> bf16; zero the f64 accumulators -------------
__global__ __launch_bounds__(256) void k_normalize(const float* __restrict__ x,
                                                   ushort* __restrict__ xu,
                                                   double* __restrict__ sums) {
    const int row = blockIdx.x;            // b*L + l
    const int t   = threadIdx.x;
    const float* xr = x + (size_t)row * D_DIM;
    f4 v0 = __builtin_nontemporal_load(((const f4*)xr) + t);        // x is single-use
    f4 v1 = __builtin_nontemporal_load(((const f4*)xr) + t + 256);
    float ss = v0.x*v0.x + v0.y*v0.y + v0.z*v0.z + v0.w*v0.w
             + v1.x*v1.x + v1.y*v1.y + v1.z*v1.z + v1.w*v1.w;
    #pragma unroll
    for (int off = 32; off; off >>= 1) ss += __shfl_down(ss, off);
    __shared__ float red[4];
    __shared__ float s_inv;
    if ((t & 63) == 0) red[t >> 6] = ss;
    __syncthreads();
    if (t == 0) {
        float nrm = sqrtf(red[0] + red[1] + red[2] + red[3]);
        nrm = fmaxf(nrm, EPSV);
        s_inv = 1.0f / nrm;
        if (row == 0) { sums[0] = 0.0; sums[1] = 0.0; sums[2] = 0.0; sums[3] = 0.0; }
    }
    __syncthreads();
    const float inv = s_inv;
    ushort* xo = xu + (size_t)row * D_DIM;
    ushort4 o0, o1;
    o0.x = f2bf(v0.x * inv); o0.y = f2bf(v0.y * inv);
    o0.z = f2bf(v0.z * inv); o0.w = f2bf(v0.w * inv);
    o1.x = f2bf(v1.x * inv); o1.y = f2bf(v1.y * inv);
    o1.z = f2bf(v1.z * inv); o1.w = f2bf(v1.w * inv);
    ((ushort4*)xo)[t]       = o0;    // cached: xu is the GEMM's hot working set
    ((ushort4*)xo)[t + 256] = o1;
}

// ---- K2 mixed grid: [0,NPAIR) sym GEMM tiles | [NPAIR,NPAIR+NRED) attn-mean reducers
__global__ __launch_bounds__(256) void k_mixed(const ushort* __restrict__ Xu,
                                               const float* __restrict__ attn,
                                               float* __restrict__ Kout,
                                               double* __restrict__ sums,
                                               ushort* __restrict__ Amean) {
    __shared__ __align__(16) ushort lds_a[2][128 * 32];
    __shared__ __align__(16) ushort lds_b[2][128 * 32];
    const int t = threadIdx.x;
    const int batch = blockIdx.z;

    if (blockIdx.x >= NPAIR) {
        // ------- reducer: Amean[b,l,c] = mean_h attn[b,h,l,c] (bf16), NT loads -------
        const int rid = blockIdx.x - NPAIR;
        const float* ab = attn + (size_t)batch * H_DIM * L_DIM * L_DIM;
        ushort* am = Amean + (size_t)batch * L_DIM * L_DIM;
        const int n4 = L_DIM * L_DIM / 4;
        for (int i = rid * 256 + t; i < n4; i += NRED * 256) {   // 8 exact iters
            float4 s = {0.f, 0.f, 0.f, 0.f};
            #pragma unroll
            for (int h = 0; h < H_DIM; ++h) {
                // attn is single-use streaming data: bypass LLC so xu/K stay resident
                const f4 v = __builtin_nontemporal_load(
                    ((const f4*)(ab + (size_t)h * L_DIM * L_DIM)) + i);
                s.x += v.x; s.y += v.y; s.z += v.z; s.w += v.w;
            }
            ushort4 o;
            o.x = f2bf(s.x * 0.125f); o.y = f2bf(s.y * 0.125f);
            o.z = f2bf(s.z * 0.125f); o.w = f2bf(s.w * 0.125f);
            ((ushort4*)am)[i] = o;               // cached: re-read by epilogue
        }
        return;
    }

    // ---------------- GEMM tile (upper-triangular + mirror), 2-phase pipelined -------
    const int lane = t & 63;
    const int w    = t >> 6;
    const int wr   = w >> 1, wc = w & 1;       // 2x2 waves, 64x64 each
    int ti = 0, rem = blockIdx.x;
    while (rem >= NT - ti) { rem -= NT - ti; ++ti; }
    const int tj = ti + rem;
    const int bRow = ti * 128;
    const int bCol = tj * 128;
    const bool diag = (ti == tj);
    const ushort* Xb = Xu + (size_t)batch * L_DIM * D_DIM;

    const int srow = t >> 2;                   // 0..63 panel row
    // store-side swizzle: LDS slot (t&3) of row srow receives chunk (t&3)^((srow>>1)&3)
    const int scol = ((t & 3) ^ ((srow >> 1) & 3)) * 8;
    const ushort* gA0 = Xb + (size_t)(bRow + srow)      * D_DIM + scol;
    const ushort* gA1 = Xb + (size_t)(bRow + 64 + srow) * D_DIM + scol;
    const ushort* gB0 = Xb + (size_t)(bCol + srow)      * D_DIM + scol;
    const ushort* gB1 = Xb + (size_t)(bCol + 64 + srow) * D_DIM + scol;
    const int ldst = t * 8;

    f32x4 acc[4][4] = {};
    const int frow = lane & 15;
    const int fk   = lane >> 4;
    const int fx   = (frow >> 1) & 3;          // read-side XOR key (conflict-free)

    auto STAGE = [&](int buf, int kt) {
        const size_t ko = (size_t)kt * 32;
        gload_lds16(gA0 + ko, &lds_a[buf][ldst]);
        gload_lds16(gA1 + ko, &lds_a[buf][64 * 32 + ldst]);
        gload_lds16(gB0 + ko, &lds_b[buf][ldst]);
        gload_lds16(gB1 + ko, &lds_b[buf][64 * 32 + ldst]);
    };
    auto COMPUTE = [&](int buf) {
        bf16x8 a[4], b[4];
        #pragma unroll
        for (int m = 0; m < 4; ++m)
            a[m] = *(const bf16x8*)&lds_a[buf][(wr * 64 + m * 16 + frow) * 32 + (fk ^ fx) * 8];
        #pragma unroll
        for (int n = 0; n < 4; ++n)
            b[n] = *(const bf16x8*)&lds_b[buf][(wc * 64 + n * 16 + frow) * 32 + (fk ^ fx) * 8];
        #pragma unroll
        for (int m = 0; m < 4; ++m)
            #pragma unroll
            for (int n = 0; n < 4; ++n)
                acc[m][n] = __builtin_amdgcn_mfma_f32_16x16x32_bf16(a[m], b[n], acc[m][n], 0, 0, 0);
    };

    STAGE(0, 0);
    __syncthreads();                           // vmcnt(0) drain: buf0 ready
    for (int kt = 0; kt < NKT; kt += 2) {
        STAGE(1, kt + 1);
        COMPUTE(0);
        __syncthreads();
        if (kt + 2 < NKT) STAGE(0, kt + 2);
        COMPUTE(1);
        __syncthreads();
    }

    float* Kb = Kout + (size_t)batch * L_DIM * L_DIM;
    float ps = 0.f, pss = 0.f;
    #pragma unroll
    for (int m = 0; m < 4; ++m) {
        #pragma unroll
        for (int n = 0; n < 4; ++n) {
            #pragma unroll
            for (int j = 0; j < 4; ++j) {
                const int r = bRow + wr * 64 + m * 16 + fk * 4 + j;
                const int c = bCol + wc * 64 + n * 16 + frow;
                const float v = acc[m][n][j];
                Kb[(size_t)r * L_DIM + c] = v;   // cached: re-read by epilogue
                ps += v; pss += v * v;
            }
            if (!diag) {
                // mirror: K[c][r..r+3] = acc[m][n][0..3] — contiguous float4
                const int rr  = bCol + wc * 64 + n * 16 + frow;
                const int cc0 = bRow + wr * 64 + m * 16 + fk * 4;
                *(float4*)&Kb[(size_t)rr * L_DIM + cc0] = *(float4*)&acc[m][n];
            }
        }
    }
    if (!diag) { ps *= 2.f; pss *= 2.f; }      // off-diag values appear twice in K
    #pragma unroll
    for (int off = 32; off; off >>= 1) {
        ps  += __shfl_down(ps, off);
        pss += __shfl_down(pss, off);
    }
    __shared__ float redS[4], redSS[4];
    if (lane == 0) { redS[w] = ps; redSS[w] = pss; }
    __syncthreads();
    if (t == 0) {
        atomicAdd(&sums[batch * 2],     (double)(redS[0] + redS[1] + redS[2] + redS[3]));
        atomicAdd(&sums[batch * 2 + 1], (double)(redSS[0] + redSS[1] + redSS[2] + redSS[3]));
    }
}

// ---------------- K3: K_norm in place; dot(Amean,K) -> cos_align, gate ---------------
__global__ __launch_bounds__(256) void k_epilogue(float* __restrict__ out,
                                                  const ushort* __restrict__ Amean,
                                                  const double* __restrict__ sums,
                                                  const float* __restrict__ Wp,
                                                  const float* __restrict__ bp) {
    const int row = blockIdx.x;              // b*L + l
    const int b = row >> 11;
    const int t = threadIdx.x;

    const double N = (double)L_DIM * (double)L_DIM;
    const double mean_d = sums[b * 2] / N;
    double var = (sums[b * 2 + 1] - N * mean_d * mean_d) / (N - 1.0);
    var = var > 0.0 ? var : 0.0;
    float sd = (float)sqrt(var);
    sd = fmaxf(sd, EPSV);
    const float inv_std = 1.0f / sd;
    const float mean = (float)mean_d;

    float* Krow = out + 2 * B_DIM * L_DIM + (size_t)row * L_DIM;
    const ushort* arow = Amean + (size_t)row * L_DIM;

    // 8 elements per thread: dot with raw K (LLC-hot), then normalize in place
    f4 k0 = ((const f4*)Krow)[t * 2];
    f4 k1 = ((const f4*)Krow)[t * 2 + 1];
    const ushort4 a0 = ((const ushort4*)arow)[t * 2];
    const ushort4 a1 = ((const ushort4*)arow)[t * 2 + 1];
    float dot = bf2f(a0.x) * k0.x + bf2f(a0.y) * k0.y + bf2f(a0.z) * k0.z + bf2f(a0.w) * k0.w
              + bf2f(a1.x) * k1.x + bf2f(a1.y) * k1.y + bf2f(a1.z) * k1.z + bf2f(a1.w) * k1.w;
    f4 n0, n1;
    n0.x = (k0.x - mean) * inv_std; n0.y = (k0.y - mean) * inv_std;
    n0.z = (k0.z - mean) * inv_std; n0.w = (k0.w - mean) * inv_std;
    n1.x = (k1.x - mean) * inv_std; n1.y = (k1.y - mean) * inv_std;
    n1.z = (k1.z - mean) * inv_std; n1.w = (k1.w - mean) * inv_std;
    // K_norm is written once and never re-read: non-temporal stores
    __builtin_nontemporal_store(n0, ((f4*)Krow) + t * 2);
    __builtin_nontemporal_store(n1, ((f4*)Krow) + t * 2 + 1);

    #pragma unroll
    for (int off = 32; off; off >>= 1) dot += __shfl_down(dot, off);
    __shared__ float red[4];
    if ((t & 63) == 0) red[t >> 6] = dot;
    __syncthreads();
    if (t == 0) {
        const float dotv = red[0] + red[1] + red[2] + red[3];
        const float ca = (dotv - mean) * inv_std;      // uses sum_c A == 1
        out[B_DIM * L_DIM + row] = ca;                 // cos_align
        const float z = Wp[0] * ca + bp[0];
        out[row] = 1.0f / (1.0f + expf(-z));           // gate
    }
}

extern "C" void kernel_launch(void* const* d_in, const int* in_sizes, int n_in,
                              void* d_out, int out_size, void* d_ws, size_t ws_size,
                              hipStream_t stream) {
    const float* x    = (const float*)d_in[0];
    const float* attn = (const float*)d_in[1];
    const float* W    = (const float*)d_in[2];
    const float* bb   = (const float*)d_in[3];
    float* out = (float*)d_out;

    const size_t XU_BYTES = (size_t)B_DIM * L_DIM * D_DIM * 2;            // 16.78 MB
    ushort* xu    = (ushort*)d_ws;
    double* sums  = (double*)((char*)d_ws + XU_BYTES);
    ushort* Amean = (ushort*)((char*)d_ws + XU_BYTES + 256);              // 16.78 MB bf16
    float*  Kbuf  = out + 2 * B_DIM * L_DIM;                              // K in K_norm slot

    hipLaunchKernelGGL(k_normalize, dim3(B_DIM * L_DIM), dim3(256), 0, stream,
                       x, xu, sums);
    hipLaunchKernelGGL(k_mixed, dim3(NPAIR + NRED, 1, B_DIM), dim3(256), 0, stream,
                       xu, attn, Kbuf, sums, Amean);
    hipLaunchKernelGGL(k_epilogue, dim3(B_DIM * L_DIM), dim3(256), 0, stream,
                       out, Amean, sums, W, bb);
}